// Round 5
// baseline (494.531 us; speedup 1.0000x reference)
//
#include <hip/hip_runtime.h>
#include <cstddef>
#include <cstdint>

#define TS 2048   // sequence length S
#define TD 512    // model dim D
#define TH 8      // heads
#define TDH 64    // head dim
#define CAP 192   // candidate entries per row; recompute fallback beyond

typedef float f32x4 __attribute__((ext_vector_type(4)));
typedef short short8v __attribute__((ext_vector_type(8)));

struct us4 { unsigned short a, b, c, d; };

__device__ __forceinline__ unsigned short f2bf(float f) {
  unsigned u = __builtin_bit_cast(unsigned, f);
  u += 0x7fff + ((u >> 16) & 1);          // RNE
  return (unsigned short)(u >> 16);
}
__device__ __forceinline__ float bf2f(unsigned short u) {
  return __builtin_bit_cast(float, (unsigned)u << 16);
}

// ---------------------------------------------------------------------------
// GEMM: C[M,N] = A[M,K] @ W[K,N] + bias[N].
// mode 0: f32 row-major to C. mode 1: bf16 head-major [b,h,s,dh] to outBf.
// ---------------------------------------------------------------------------
__global__ __launch_bounds__(256) void gemm_bias(
    const float* __restrict__ A, const float* __restrict__ W,
    const float* __restrict__ bias, float* __restrict__ C,
    short* __restrict__ outBf, int mode,
    int M, int N, int Kd)
{
  __shared__ float As[16][68];
  __shared__ float Bs[16][68];

  const int tid = threadIdx.x;
  const int tx = tid & 15;
  const int ty = tid >> 4;
  const int rowBase = blockIdx.x * 64;
  const int colBase = blockIdx.y * 64;

  const int ar = tid >> 2;
  const int ac = (tid & 3) << 2;
  const int brk = tid >> 4;
  const int bc  = (tid & 15) << 2;

  float acc[4][4] = {};

  for (int kt = 0; kt < Kd; kt += 16) {
    float4 av = *(const float4*)&A[(size_t)(rowBase + ar) * Kd + kt + ac];
    float4 bv = *(const float4*)&W[(size_t)(kt + brk) * N + colBase + bc];
    As[ac + 0][ar] = av.x;
    As[ac + 1][ar] = av.y;
    As[ac + 2][ar] = av.z;
    As[ac + 3][ar] = av.w;
    *(float4*)&Bs[brk][bc] = bv;
    __syncthreads();
#pragma unroll
    for (int k = 0; k < 16; ++k) {
      float4 a = *(const float4*)&As[k][ty << 2];
      float4 b = *(const float4*)&Bs[k][tx << 2];
      acc[0][0] += a.x * b.x; acc[0][1] += a.x * b.y; acc[0][2] += a.x * b.z; acc[0][3] += a.x * b.w;
      acc[1][0] += a.y * b.x; acc[1][1] += a.y * b.y; acc[1][2] += a.y * b.z; acc[1][3] += a.y * b.w;
      acc[2][0] += a.z * b.x; acc[2][1] += a.z * b.y; acc[2][2] += a.z * b.z; acc[2][3] += a.z * b.w;
      acc[3][0] += a.w * b.x; acc[3][1] += a.w * b.y; acc[3][2] += a.w * b.z; acc[3][3] += a.w * b.w;
    }
    __syncthreads();
  }

  float4 bb = *(const float4*)&bias[colBase + (tx << 2)];
  if (mode == 0) {
#pragma unroll
    for (int i = 0; i < 4; ++i) {
      float4 o;
      o.x = acc[i][0] + bb.x;
      o.y = acc[i][1] + bb.y;
      o.z = acc[i][2] + bb.z;
      o.w = acc[i][3] + bb.w;
      *(float4*)&C[(size_t)(rowBase + (ty << 2) + i) * N + colBase + (tx << 2)] = o;
    }
  } else {
#pragma unroll
    for (int i = 0; i < 4; ++i) {
      const int row = rowBase + (ty << 2) + i;
      const int col = colBase + (tx << 2);
      const int bI = row >> 11, s = row & 2047;
      const int hI = col >> 6, dh = col & 63;
      us4 o;
      o.a = f2bf(acc[i][0] + bb.x);
      o.b = f2bf(acc[i][1] + bb.y);
      o.c = f2bf(acc[i][2] + bb.z);
      o.d = f2bf(acc[i][3] + bb.w);
      *(us4*)(outBf + (((size_t)(bI * TH + hI) * TS + s) * TDH + dh)) = o;
    }
  }
}

// ---------------------------------------------------------------------------
// Fused attention v3: chunked accumulators for occupancy.
// Block = (16 q-rows, pair), 256 threads = 4 waves; wave owns 512 cols,
// processed as 4 chunks of 128. Candidates (z > runmax-1, superset of
// support) compacted online to LDS. Michelot on compacted list per 16-lane
// group. Batched sparse PV. Recompute-based dense fallback on overflow.
// MFMA C/D: col = lane&15, row = (lane>>4)*4 + reg.
// ---------------------------------------------------------------------------
__global__ __launch_bounds__(256, 4) void fused_attn(
    const short* __restrict__ Qh, const short* __restrict__ Kh,
    const float* __restrict__ V, float* __restrict__ heads,
    float* __restrict__ avg)
{
  __shared__ int   idxS[16][CAP];
  __shared__ float valS[16][CAP];          // overlaid as zrow (2048 f) in fallback
  __shared__ float redMax[4][16];
  __shared__ float redA[4], redB[4], redMx[4];
  __shared__ int   cntS[16];
  __shared__ float tauS[16];
  __shared__ float qrowS[TDH];

  const int tid  = threadIdx.x;
  const int w    = tid >> 6;
  const int lane = tid & 63;
  const int g    = lane >> 4;
  const int lc16 = lane & 15;
  const int pair = blockIdx.y;
  const int b    = pair >> 3;
  const int h    = pair & 7;
  const int q0   = blockIdx.x * 16;
  const int wcol0 = w * 512;

  const short* Qbase = Qh + ((size_t)pair * TS + q0) * TDH;
  short8v aq0 = *(const short8v*)(Qbase + lc16 * TDH + g * 8);
  short8v aq1 = *(const short8v*)(Qbase + lc16 * TDH + 32 + g * 8);

  const short* Kb = Kh + (size_t)pair * TS * TDH;
  const float* Vb = V + (size_t)b * TS * TDH;

  if (tid < 16) cntS[tid] = 0;
  __syncthreads();

  // ---- A: QK^T in 4 chunks of 128 cols, online candidate admission ----
  float runmax[4] = {-1e30f, -1e30f, -1e30f, -1e30f};
  for (int c = 0; c < 4; ++c) {
    const int cb = wcol0 + c * 128;
    f32x4 acc[8];
#pragma unroll
    for (int t = 0; t < 8; ++t) acc[t] = (f32x4){0.f, 0.f, 0.f, 0.f};
#pragma unroll
    for (int t = 0; t < 8; ++t) {
      const short* kp = Kb + (size_t)(cb + t * 16 + lc16) * TDH + g * 8;
      short8v b0 = *(const short8v*)(kp);
      short8v b1 = *(const short8v*)(kp + 32);
      acc[t] = __builtin_amdgcn_mfma_f32_16x16x32_bf16(aq0, b0, acc[t], 0, 0, 0);
      acc[t] = __builtin_amdgcn_mfma_f32_16x16x32_bf16(aq1, b1, acc[t], 0, 0, 0);
    }
    // chunk row-max -> running max
    float cm[4] = {-1e30f, -1e30f, -1e30f, -1e30f};
#pragma unroll
    for (int t = 0; t < 8; ++t)
#pragma unroll
      for (int i = 0; i < 4; ++i) cm[i] = fmaxf(cm[i], acc[t][i]);
#pragma unroll
    for (int m = 1; m < 16; m <<= 1)
#pragma unroll
      for (int i = 0; i < 4; ++i) cm[i] = fmaxf(cm[i], __shfl_xor(cm[i], m));
#pragma unroll
    for (int i = 0; i < 4; ++i) runmax[i] = fmaxf(runmax[i], cm[i]);
    // admit candidates: z > runmax - 1 (superset of final support)
#pragma unroll
    for (int t = 0; t < 8; ++t)
#pragma unroll
      for (int i = 0; i < 4; ++i) {
        const float v = acc[t][i];
        if (v > runmax[i] - 1.f) {
          const int row = g * 4 + i;
          const int pos = atomicAdd(&cntS[row], 1);
          if (pos < CAP) { idxS[row][pos] = cb + t * 16 + lc16; valS[row][pos] = v; }
        }
      }
  }
  if (lc16 == 0)
#pragma unroll
    for (int i = 0; i < 4; ++i) redMax[w][g * 4 + i] = runmax[i];
  __syncthreads();

  // ---- D: per-group Michelot on candidate list (no block barriers) ----
  {
    const int rw = w * 4 + g;
    const int cnt = cntS[rw];
    float tau_r = fmaxf(fmaxf(redMax[0][rw], redMax[1][rw]),
                        fmaxf(redMax[2][rw], redMax[3][rw])) - 1.0f;
    if (cnt <= CAP) {
      float cv[CAP / 16];
#pragma unroll
      for (int e = 0; e < CAP / 16; ++e) {
        const int ii = lc16 + e * 16;
        cv[e] = (ii < cnt) ? valS[rw][ii] : -1e30f;
      }
      int prevc = -1;
      for (int it = 0; it < 64; ++it) {
        float s = 0.f, c = 0.f;
#pragma unroll
        for (int e = 0; e < CAP / 16; ++e) {
          const float v = cv[e];
          if (v > tau_r) { s += v; c += 1.f; }
        }
#pragma unroll
        for (int m = 1; m < 16; m <<= 1) {
          s += __shfl_xor(s, m);
          c += __shfl_xor(c, m);
        }
        tau_r = (s - 1.f) / c;
        const int ci = (int)c;
        if (ci == prevc) break;
        prevc = ci;
      }
    }
    if (lc16 == 0) tauS[rw] = tau_r;   // same-wave readers: ordered
  }

  // ---- E: avg scatter + batched sparse PV for this wave's 4 rows ----
  float apv[4] = {0.f, 0.f, 0.f, 0.f};
#pragma unroll
  for (int rr = 0; rr < 4; ++rr) {
    const int r = w * 4 + rr;
    const int cnt = cntS[r];
    if (cnt > CAP) continue;                   // fallback handles
    const float tau_r = tauS[r];
    float* avgRow = avg + ((size_t)b * TS + q0 + r) * TS;
    for (int e = lane; e < cnt; e += 64) {
      const float p = valS[r][e] - tau_r;
      if (p > 0.f) atomicAdd(avgRow + idxS[r][e], p * 0.125f);
    }
    float a = 0.f;
    for (int e0 = 0; e0 < cnt; e0 += 8) {
      float pb[8], vb8[8];
#pragma unroll
      for (int u = 0; u < 8; ++u) {
        const int e = e0 + u;
        const int ec = (e < cnt) ? e : 0;
        pb[u] = (e < cnt) ? (valS[r][ec] - tau_r) : 0.f;
        vb8[u] = Vb[(size_t)idxS[r][ec] * TDH + lane];
      }
#pragma unroll
      for (int u = 0; u < 8; ++u) a += fmaxf(pb[u], 0.f) * vb8[u];
    }
    apv[rr] = a;
  }

  // ---- F: dense fallback for overflowed rows (recompute; rare) ----
  __syncthreads();                              // normal rows done with valS/idxS
  float* zrow = &valS[0][0];                    // 16*CAP >= 2048 floats
  float (*hpart)[64] = (float(*)[64])&idxS[0][0];
  for (int r = 0; r < 16; ++r) {
    if (cntS[r] <= CAP) continue;               // uniform branch
    if (tid < TDH) qrowS[tid] = bf2f((unsigned short)Qbase[r * TDH + tid]);
    __syncthreads();
    // recompute z: thread covers cols tid*8..tid*8+7
    for (int u = 0; u < 8; ++u) {
      const int j = tid * 8 + u;
      const short* kr = Kb + (size_t)j * TDH;
      float s = 0.f;
      for (int d = 0; d < TDH; ++d) s += qrowS[d] * bf2f((unsigned short)kr[d]);
      zrow[j] = s;
    }
    __syncthreads();
    float lmax = -1e30f;
#pragma unroll
    for (int jj = 0; jj < 8; ++jj) lmax = fmaxf(lmax, zrow[(jj << 8) + tid]);
    for (int off = 32; off; off >>= 1) lmax = fmaxf(lmax, __shfl_down(lmax, off));
    if (lane == 0) redMx[w] = lmax;
    __syncthreads();
    float tau = fmaxf(fmaxf(redMx[0], redMx[1]), fmaxf(redMx[2], redMx[3])) - 1.0f;
    int prevc = -1;
    for (int it = 0; it < 64; ++it) {
      float ls = 0.f, lc = 0.f;
#pragma unroll
      for (int jj = 0; jj < 8; ++jj) {
        const float v = zrow[(jj << 8) + tid];
        if (v > tau) { ls += v; lc += 1.f; }
      }
      for (int off = 32; off; off >>= 1) {
        ls += __shfl_down(ls, off);
        lc += __shfl_down(lc, off);
      }
      if (lane == 0) { redA[w] = ls; redB[w] = lc; }
      __syncthreads();
      const float ts = redA[0] + redA[1] + redA[2] + redA[3];
      const float tc = redB[0] + redB[1] + redB[2] + redB[3];
      tau = (ts - 1.f) / tc;
      const int ci = (int)tc;
      __syncthreads();
      if (ci == prevc) break;
      prevc = ci;
    }
    float* avgRow = avg + ((size_t)b * TS + q0 + r) * TS;
#pragma unroll
    for (int jj = 0; jj < 8; ++jj) {
      const int j = (jj << 8) + tid;
      const float p = zrow[j] - tau;
      if (p > 0.f) atomicAdd(avgRow + j, p * 0.125f);
    }
    float a = 0.f;
    for (int j = 0; j < 512; ++j) {
      const float p = zrow[wcol0 + j] - tau;
      if (p > 0.f) a += p * Vb[(size_t)(wcol0 + j) * TDH + lane];
    }
    hpart[w][lane] = a;
    __syncthreads();
    if (w == 0)
      heads[((size_t)b * TS + q0 + r) * TD + h * TDH + lane] =
          (hpart[0][lane] + hpart[1][lane]) + (hpart[2][lane] + hpart[3][lane]);
    __syncthreads();                            // zrow/hpart reused next r
  }

  // ---- write heads for normal rows ----
#pragma unroll
  for (int rr = 0; rr < 4; ++rr) {
    const int r = w * 4 + rr;
    if (cntS[r] <= CAP)
      heads[((size_t)b * TS + q0 + r) * TD + h * TDH + lane] = apv[rr];
  }
}

// ---------------------------------------------------------------------------
extern "C" void kernel_launch(void* const* d_in, const int* in_sizes, int n_in,
                              void* d_out, int out_size, void* d_ws, size_t ws_size,
                              hipStream_t stream) {
  (void)in_sizes; (void)n_in; (void)out_size; (void)ws_size;

  const float* x    = (const float*)d_in[0];
  const float* Wq   = (const float*)d_in[1];
  const float* bq   = (const float*)d_in[2];
  const float* Wk   = (const float*)d_in[3];
  const float* bk   = (const float*)d_in[4];
  const float* Wv   = (const float*)d_in[5];
  const float* bv   = (const float*)d_in[6];
  const float* Wout = (const float*)d_in[7];
  const float* bout = (const float*)d_in[8];

  float* out   = (float*)d_out;
  float* x_out = out;                       // [2,2048,512]
  float* avg   = out + 2097152;             // [2,2048,2048]

  float* ws = (float*)d_ws;
  float* Vb = ws;                           // f32 [2][2048][64]
  float* Hd = ws + 262144;                  // f32 [4096][512]
  short* Qh = (short*)(ws + 2359296);       // bf16 [16][2048][64]
  short* Kh = (short*)(ws + 3407872);       // bf16 [16][2048][64]

  const dim3 blk(256);
  const int BS = 2 * TS;

  gemm_bias<<<dim3(BS / 64, TD / 64), blk, 0, stream>>>(x, Wq, bq, nullptr, Qh, 1, BS, TD, TD);
  gemm_bias<<<dim3(BS / 64, TD / 64), blk, 0, stream>>>(x, Wk, bk, nullptr, Kh, 1, BS, TD, TD);
  gemm_bias<<<dim3(BS / 64, TDH / 64), blk, 0, stream>>>(x, Wv, bv, Vb, nullptr, 0, BS, TDH, TD);

  hipMemsetAsync(avg, 0, (size_t)2 * TS * TS * sizeof(float), stream);

  fused_attn<<<dim3(TS / 16, 16), blk, 0, stream>>>(Qh, Kh, Vb, Hd, avg);

  gemm_bias<<<dim3(BS / 64, TD / 64), blk, 0, stream>>>(Hd, Wout, bout, x_out, nullptr, 0, BS, TD, TD);
}

// Round 6
// 318.024 us; speedup vs baseline: 1.5550x; 1.5550x over previous
//
#include <hip/hip_runtime.h>
#include <cstddef>
#include <cstdint>

#define TS 2048   // sequence length S
#define TD 512    // model dim D
#define TH 8      // heads
#define TDH 64    // head dim
#define CAP 128   // candidate entries per row (z > zmax-1); recompute fallback beyond

typedef float f32x4 __attribute__((ext_vector_type(4)));
typedef short short8v __attribute__((ext_vector_type(8)));

__device__ __forceinline__ unsigned short f2bf(float f) {
  unsigned u = __builtin_bit_cast(unsigned, f);
  u += 0x7fff + ((u >> 16) & 1);          // RNE
  return (unsigned short)(u >> 16);
}
__device__ __forceinline__ float bf2f(unsigned short u) {
  return __builtin_bit_cast(float, (unsigned)u << 16);
}

// ---------------------------------------------------------------------------
// bf16-MFMA GEMM: C[M,N] = A[M,K] @ W[K,N] + bias[N].
// A: f32 (aIsBf16=0, converted at stage time) or bf16 (aIsBf16=1).
// W: f32, converted at stage time. 64x64 tile, BK=32, 4 waves (2x2 of 32x32).
// mode 0: f32 row-major to Cf. mode 1: bf16 head-major [b,h,s,dh] to Cbf.
// MFMA frags: A[row=lc16][k=g*8+j], B[col=lc16][k=g*8+j]; C/D col=lane&15,
// row=(lane>>4)*4+reg (m89-verified, same convention proven in R3/R4 attn).
// ---------------------------------------------------------------------------
__global__ __launch_bounds__(256) void gemm_mfma(
    const void* __restrict__ A, int aIsBf16,
    const float* __restrict__ W, const float* __restrict__ bias,
    float* __restrict__ Cf, short* __restrict__ Cbf, int mode,
    int M, int N, int Kd)
{
  __shared__ short As[64][40];   // [m][k], stride 80B: 16B-aligned, ~2-way banks
  __shared__ short Bs[64][40];   // [n][k] (transposed W tile)

  const int tid  = threadIdx.x;
  const int w    = tid >> 6;
  const int lane = tid & 63;
  const int g    = lane >> 4;
  const int lc16 = lane & 15;
  const int wm   = w >> 1;       // wave row 0..1
  const int wn   = w & 1;        // wave col 0..1
  const int row0 = blockIdx.x * 64;
  const int col0 = blockIdx.y * 64;

  // stage mappings
  const int ar = tid >> 2;            // A row 0..63
  const int ak = (tid & 3) << 3;      // A k 0,8,16,24
  const int wk = tid >> 3;            // W k-row 0..31
  const int wn8 = (tid & 7) << 3;     // W n 0..56

  f32x4 acc[2][2];
#pragma unroll
  for (int i = 0; i < 2; ++i)
#pragma unroll
    for (int j = 0; j < 2; ++j) acc[i][j] = (f32x4){0.f, 0.f, 0.f, 0.f};

  for (int kt = 0; kt < Kd; kt += 32) {
    // A tile 64x32
    if (aIsBf16) {
      short8v v = *(const short8v*)((const short*)A + (size_t)(row0 + ar) * Kd + kt + ak);
      *(short8v*)&As[ar][ak] = v;
    } else {
      const float* ap = (const float*)A + (size_t)(row0 + ar) * Kd + kt + ak;
      float4 f0 = *(const float4*)ap;
      float4 f1 = *(const float4*)(ap + 4);
      short8v v;
      v[0] = (short)f2bf(f0.x); v[1] = (short)f2bf(f0.y);
      v[2] = (short)f2bf(f0.z); v[3] = (short)f2bf(f0.w);
      v[4] = (short)f2bf(f1.x); v[5] = (short)f2bf(f1.y);
      v[6] = (short)f2bf(f1.z); v[7] = (short)f2bf(f1.w);
      *(short8v*)&As[ar][ak] = v;
    }
    // W tile 32x64, transposed into Bs[n][k]
    {
      const float* wp = W + (size_t)(kt + wk) * N + col0 + wn8;
      float4 f0 = *(const float4*)wp;
      float4 f1 = *(const float4*)(wp + 4);
      Bs[wn8 + 0][wk] = (short)f2bf(f0.x);
      Bs[wn8 + 1][wk] = (short)f2bf(f0.y);
      Bs[wn8 + 2][wk] = (short)f2bf(f0.z);
      Bs[wn8 + 3][wk] = (short)f2bf(f0.w);
      Bs[wn8 + 4][wk] = (short)f2bf(f1.x);
      Bs[wn8 + 5][wk] = (short)f2bf(f1.y);
      Bs[wn8 + 6][wk] = (short)f2bf(f1.z);
      Bs[wn8 + 7][wk] = (short)f2bf(f1.w);
    }
    __syncthreads();

    short8v a0 = *(const short8v*)&As[wm * 32 + lc16][g * 8];
    short8v a1 = *(const short8v*)&As[wm * 32 + 16 + lc16][g * 8];
    short8v b0 = *(const short8v*)&Bs[wn * 32 + lc16][g * 8];
    short8v b1 = *(const short8v*)&Bs[wn * 32 + 16 + lc16][g * 8];
    acc[0][0] = __builtin_amdgcn_mfma_f32_16x16x32_bf16(a0, b0, acc[0][0], 0, 0, 0);
    acc[0][1] = __builtin_amdgcn_mfma_f32_16x16x32_bf16(a0, b1, acc[0][1], 0, 0, 0);
    acc[1][0] = __builtin_amdgcn_mfma_f32_16x16x32_bf16(a1, b0, acc[1][0], 0, 0, 0);
    acc[1][1] = __builtin_amdgcn_mfma_f32_16x16x32_bf16(a1, b1, acc[1][1], 0, 0, 0);
    __syncthreads();
  }

#pragma unroll
  for (int ni = 0; ni < 2; ++ni) {
    const int ocol = col0 + wn * 32 + ni * 16 + lc16;
    const float bb = bias[ocol];
#pragma unroll
    for (int mi = 0; mi < 2; ++mi)
#pragma unroll
      for (int r = 0; r < 4; ++r) {
        const int orow = row0 + wm * 32 + mi * 16 + g * 4 + r;
        const float val = acc[mi][ni][r] + bb;
        if (mode == 0) {
          Cf[(size_t)orow * N + ocol] = val;
        } else {
          const int bI = orow >> 11, s = orow & 2047;
          const int hI = ocol >> 6, dh = ocol & 63;
          Cbf[(((size_t)(bI * TH + hI) * TS + s) * TDH) + dh] = (short)f2bf(val);
        }
      }
  }
}

// ---------------------------------------------------------------------------
// Fused attention v4: two-pass QK^T (low regs, GLOBAL threshold).
// Block = (16 q-rows, pair), 256 threads = 4 waves; wave owns 512 cols as
// 4 chunks of 128. Pass 1: row maxima only. Pass 2: recompute, admit
// z > zmax-1 (exact candidate superset). Michelot per 16-lane group on the
// list; batched sparse PV; recompute dense fallback on overflow (rare).
// ---------------------------------------------------------------------------
__global__ __launch_bounds__(256, 4) void fused_attn(
    const short* __restrict__ Qh, const short* __restrict__ Kh,
    const float* __restrict__ V, short* __restrict__ heads,
    float* __restrict__ avg)
{
  __shared__ int   idxS[16][CAP];
  __shared__ float valS[16][CAP];          // overlaid as zrow (2048 f) in fallback
  __shared__ float redMax[4][16];
  __shared__ float redA[4], redB[4], redMx[4];
  __shared__ int   cntS[16];
  __shared__ float tauS[16];
  __shared__ float qrowS[TDH];

  const int tid  = threadIdx.x;
  const int w    = tid >> 6;
  const int lane = tid & 63;
  const int g    = lane >> 4;
  const int lc16 = lane & 15;
  const int pair = blockIdx.y;
  const int b    = pair >> 3;
  const int h    = pair & 7;
  const int q0   = blockIdx.x * 16;
  const int wcol0 = w * 512;

  const short* Qbase = Qh + ((size_t)pair * TS + q0) * TDH;
  short8v aq0 = *(const short8v*)(Qbase + lc16 * TDH + g * 8);
  short8v aq1 = *(const short8v*)(Qbase + lc16 * TDH + 32 + g * 8);

  const short* Kb = Kh + (size_t)pair * TS * TDH;
  const float* Vb = V + (size_t)b * TS * TDH;

  if (tid < 16) cntS[tid] = 0;

  // ---- pass 1: row maxima (accumulators discarded) ----
  float runmax[4] = {-1e30f, -1e30f, -1e30f, -1e30f};
  for (int c = 0; c < 4; ++c) {
    const int cb = wcol0 + c * 128;
    f32x4 acc[8];
#pragma unroll
    for (int t = 0; t < 8; ++t) acc[t] = (f32x4){0.f, 0.f, 0.f, 0.f};
#pragma unroll
    for (int t = 0; t < 8; ++t) {
      const short* kp = Kb + (size_t)(cb + t * 16 + lc16) * TDH + g * 8;
      short8v b0 = *(const short8v*)(kp);
      short8v b1 = *(const short8v*)(kp + 32);
      acc[t] = __builtin_amdgcn_mfma_f32_16x16x32_bf16(aq0, b0, acc[t], 0, 0, 0);
      acc[t] = __builtin_amdgcn_mfma_f32_16x16x32_bf16(aq1, b1, acc[t], 0, 0, 0);
    }
#pragma unroll
    for (int t = 0; t < 8; ++t)
#pragma unroll
      for (int i = 0; i < 4; ++i) runmax[i] = fmaxf(runmax[i], acc[t][i]);
  }
#pragma unroll
  for (int m = 1; m < 16; m <<= 1)
#pragma unroll
    for (int i = 0; i < 4; ++i) runmax[i] = fmaxf(runmax[i], __shfl_xor(runmax[i], m));
  if (lc16 == 0)
#pragma unroll
    for (int i = 0; i < 4; ++i) redMax[w][g * 4 + i] = runmax[i];
  __syncthreads();

  float tau0[4];
#pragma unroll
  for (int i = 0; i < 4; ++i) {
    const int r = g * 4 + i;
    tau0[i] = fmaxf(fmaxf(redMax[0][r], redMax[1][r]),
                    fmaxf(redMax[2][r], redMax[3][r])) - 1.0f;
  }

  // ---- pass 2: recompute, admit exact candidate set ----
  for (int c = 0; c < 4; ++c) {
    const int cb = wcol0 + c * 128;
    f32x4 acc[8];
#pragma unroll
    for (int t = 0; t < 8; ++t) acc[t] = (f32x4){0.f, 0.f, 0.f, 0.f};
#pragma unroll
    for (int t = 0; t < 8; ++t) {
      const short* kp = Kb + (size_t)(cb + t * 16 + lc16) * TDH + g * 8;
      short8v b0 = *(const short8v*)(kp);
      short8v b1 = *(const short8v*)(kp + 32);
      acc[t] = __builtin_amdgcn_mfma_f32_16x16x32_bf16(aq0, b0, acc[t], 0, 0, 0);
      acc[t] = __builtin_amdgcn_mfma_f32_16x16x32_bf16(aq1, b1, acc[t], 0, 0, 0);
    }
#pragma unroll
    for (int t = 0; t < 8; ++t)
#pragma unroll
      for (int i = 0; i < 4; ++i) {
        const float v = acc[t][i];
        if (v > tau0[i]) {
          const int row = g * 4 + i;
          const int pos = atomicAdd(&cntS[row], 1);
          if (pos < CAP) { idxS[row][pos] = cb + t * 16 + lc16; valS[row][pos] = v; }
        }
      }
  }
  __syncthreads();

  // ---- Michelot per 16-lane group on row rw = w*4+g (no block barriers) ----
  {
    const int rw = w * 4 + g;
    const int cnt = cntS[rw];
    float tau_r = fmaxf(fmaxf(redMax[0][rw], redMax[1][rw]),
                        fmaxf(redMax[2][rw], redMax[3][rw])) - 1.0f;
    if (cnt <= CAP) {
      float cv[CAP / 16];
#pragma unroll
      for (int e = 0; e < CAP / 16; ++e) {
        const int ii = lc16 + e * 16;
        cv[e] = (ii < cnt) ? valS[rw][ii] : -1e30f;
      }
      int prevc = -1;
      for (int it = 0; it < 64; ++it) {
        float s = 0.f, c = 0.f;
#pragma unroll
        for (int e = 0; e < CAP / 16; ++e) {
          const float v = cv[e];
          if (v > tau_r) { s += v; c += 1.f; }
        }
#pragma unroll
        for (int m = 1; m < 16; m <<= 1) {
          s += __shfl_xor(s, m);
          c += __shfl_xor(c, m);
        }
        tau_r = (s - 1.f) / c;
        const int ci = (int)c;
        if (ci == prevc) break;
        prevc = ci;
      }
    }
    if (lc16 == 0) tauS[rw] = tau_r;   // same-wave readers: ordered
  }

  // ---- avg scatter + batched sparse PV for this wave's 4 rows ----
  float apv[4] = {0.f, 0.f, 0.f, 0.f};
#pragma unroll
  for (int rr = 0; rr < 4; ++rr) {
    const int r = w * 4 + rr;
    const int cnt = cntS[r];
    if (cnt > CAP) continue;                   // fallback handles
    const float tau_r = tauS[r];
    float* avgRow = avg + ((size_t)b * TS + q0 + r) * TS;
    for (int e = lane; e < cnt; e += 64) {
      const float p = valS[r][e] - tau_r;
      if (p > 0.f) atomicAdd(avgRow + idxS[r][e], p * 0.125f);
    }
    float a = 0.f;
    for (int e0 = 0; e0 < cnt; e0 += 8) {
      float pb[8], vb8[8];
#pragma unroll
      for (int u = 0; u < 8; ++u) {
        const int e = e0 + u;
        const int ec = (e < cnt) ? e : 0;
        pb[u] = (e < cnt) ? (valS[r][ec] - tau_r) : 0.f;
        vb8[u] = Vb[(size_t)idxS[r][ec] * TDH + lane];
      }
#pragma unroll
      for (int u = 0; u < 8; ++u) a += fmaxf(pb[u], 0.f) * vb8[u];
    }
    apv[rr] = a;
  }

  // ---- dense fallback for overflowed rows (recompute; rare) ----
  __syncthreads();                              // normal rows done with valS/idxS
  float* zrow = &valS[0][0];                    // 16*CAP = 2048 floats
  float (*hpart)[64] = (float(*)[64])&idxS[0][0];
  for (int r = 0; r < 16; ++r) {
    if (cntS[r] <= CAP) continue;               // uniform branch
    if (tid < TDH) qrowS[tid] = bf2f((unsigned short)Qbase[r * TDH + tid]);
    __syncthreads();
    for (int u = 0; u < 8; ++u) {
      const int j = tid * 8 + u;
      const short* kr = Kb + (size_t)j * TDH;
      float s = 0.f;
      for (int d = 0; d < TDH; ++d) s += qrowS[d] * bf2f((unsigned short)kr[d]);
      zrow[j] = s;
    }
    __syncthreads();
    float lmax = -1e30f;
#pragma unroll
    for (int jj = 0; jj < 8; ++jj) lmax = fmaxf(lmax, zrow[(jj << 8) + tid]);
    for (int off = 32; off; off >>= 1) lmax = fmaxf(lmax, __shfl_down(lmax, off));
    if (lane == 0) redMx[w] = lmax;
    __syncthreads();
    float tau = fmaxf(fmaxf(redMx[0], redMx[1]), fmaxf(redMx[2], redMx[3])) - 1.0f;
    int prevc = -1;
    for (int it = 0; it < 64; ++it) {
      float ls = 0.f, lc = 0.f;
#pragma unroll
      for (int jj = 0; jj < 8; ++jj) {
        const float v = zrow[(jj << 8) + tid];
        if (v > tau) { ls += v; lc += 1.f; }
      }
      for (int off = 32; off; off >>= 1) {
        ls += __shfl_down(ls, off);
        lc += __shfl_down(lc, off);
      }
      if (lane == 0) { redA[w] = ls; redB[w] = lc; }
      __syncthreads();
      const float ts = redA[0] + redA[1] + redA[2] + redA[3];
      const float tc = redB[0] + redB[1] + redB[2] + redB[3];
      tau = (ts - 1.f) / tc;
      const int ci = (int)tc;
      __syncthreads();
      if (ci == prevc) break;
      prevc = ci;
    }
    float* avgRow = avg + ((size_t)b * TS + q0 + r) * TS;
#pragma unroll
    for (int jj = 0; jj < 8; ++jj) {
      const int j = (jj << 8) + tid;
      const float p = zrow[j] - tau;
      if (p > 0.f) atomicAdd(avgRow + j, p * 0.125f);
    }
    float a = 0.f;
    for (int j = 0; j < 512; ++j) {
      const float p = zrow[wcol0 + j] - tau;
      if (p > 0.f) a += p * Vb[(size_t)(wcol0 + j) * TDH + lane];
    }
    hpart[w][lane] = a;
    __syncthreads();
    if (w == 0)
      heads[((size_t)b * TS + q0 + r) * TD + h * TDH + lane] =
          (short)f2bf((hpart[0][lane] + hpart[1][lane]) +
                      (hpart[2][lane] + hpart[3][lane]));
    __syncthreads();                            // zrow/hpart reused next r
  }

  // ---- write heads (bf16) for normal rows ----
#pragma unroll
  for (int rr = 0; rr < 4; ++rr) {
    const int r = w * 4 + rr;
    if (cntS[r] <= CAP)
      heads[((size_t)b * TS + q0 + r) * TD + h * TDH + lane] = (short)f2bf(apv[rr]);
  }
}

// ---------------------------------------------------------------------------
extern "C" void kernel_launch(void* const* d_in, const int* in_sizes, int n_in,
                              void* d_out, int out_size, void* d_ws, size_t ws_size,
                              hipStream_t stream) {
  (void)in_sizes; (void)n_in; (void)out_size; (void)ws_size;

  const float* x    = (const float*)d_in[0];
  const float* Wq   = (const float*)d_in[1];
  const float* bq   = (const float*)d_in[2];
  const float* Wk   = (const float*)d_in[3];
  const float* bk   = (const float*)d_in[4];
  const float* Wv   = (const float*)d_in[5];
  const float* bv   = (const float*)d_in[6];
  const float* Wout = (const float*)d_in[7];
  const float* bout = (const float*)d_in[8];

  float* out   = (float*)d_out;
  float* x_out = out;                       // [2,2048,512]
  float* avg   = out + 2097152;             // [2,2048,2048]

  float* ws = (float*)d_ws;
  float* Vb = ws;                           // f32 [2][2048][64]   (262144 fl)
  short* Hd = (short*)(ws + 262144);        // bf16 [4096][512]    (1048576 fl)
  short* Qh = (short*)(ws + 1310720);       // bf16 [16][2048][64] (1048576 fl)
  short* Kh = (short*)(ws + 2359296);       // bf16 [16][2048][64] (1048576 fl)

  const dim3 blk(256);
  const int BS = 2 * TS;                    // 4096 rows

  // projections (bf16 MFMA, stage-time conversion)
  gemm_mfma<<<dim3(BS / 64, TD / 64), blk, 0, stream>>>(x, 0, Wq, bq, nullptr, Qh, 1, BS, TD, TD);
  gemm_mfma<<<dim3(BS / 64, TD / 64), blk, 0, stream>>>(x, 0, Wk, bk, nullptr, Kh, 1, BS, TD, TD);
  gemm_mfma<<<dim3(BS / 64, TDH / 64), blk, 0, stream>>>(x, 0, Wv, bv, Vb, nullptr, 0, BS, TDH, TD);

  hipMemsetAsync(avg, 0, (size_t)2 * TS * TS * sizeof(float), stream);

  fused_attn<<<dim3(TS / 16, 16), blk, 0, stream>>>(Qh, Kh, Vb, Hd, avg);

  // output projection (A = bf16 heads)
  gemm_mfma<<<dim3(BS / 64, TD / 64), blk, 0, stream>>>(Hd, 1, Wout, bout, x_out, nullptr, 0, BS, TD, TD);
}

// Round 7
// 297.733 us; speedup vs baseline: 1.6610x; 1.0682x over previous
//
#include <hip/hip_runtime.h>
#include <cstddef>
#include <cstdint>

#define TS 2048   // sequence length S
#define TD 512    // model dim D
#define TH 8      // heads
#define TDH 64    // head dim
#define ROWS 64   // q-rows per block
#define CHUNK 128 // k-cols staged per LDS chunk
#define NCH (TS / CHUNK)
#define CAP 96    // candidate entries per row (z > zmax-1); dense fallback beyond

typedef float f32x4 __attribute__((ext_vector_type(4)));
typedef short short8v __attribute__((ext_vector_type(8)));

__device__ __forceinline__ unsigned short f2bf(float f) {
  unsigned u = __builtin_bit_cast(unsigned, f);
  u += 0x7fff + ((u >> 16) & 1);          // RNE
  return (unsigned short)(u >> 16);
}
__device__ __forceinline__ float bf2f(unsigned short u) {
  return __builtin_bit_cast(float, (unsigned)u << 16);
}

// ---------------------------------------------------------------------------
// bf16-MFMA GEMM (unchanged from R6, proven): C = A @ W + bias.
// ---------------------------------------------------------------------------
__global__ __launch_bounds__(256) void gemm_mfma(
    const void* __restrict__ A, int aIsBf16,
    const float* __restrict__ W, const float* __restrict__ bias,
    float* __restrict__ Cf, short* __restrict__ Cbf, int mode,
    int M, int N, int Kd)
{
  __shared__ short As[64][40];
  __shared__ short Bs[64][40];

  const int tid  = threadIdx.x;
  const int w    = tid >> 6;
  const int lane = tid & 63;
  const int g    = lane >> 4;
  const int lc16 = lane & 15;
  const int wm   = w >> 1;
  const int wn   = w & 1;
  const int row0 = blockIdx.x * 64;
  const int col0 = blockIdx.y * 64;

  const int ar = tid >> 2;
  const int ak = (tid & 3) << 3;
  const int wk = tid >> 3;
  const int wn8 = (tid & 7) << 3;

  f32x4 acc[2][2];
#pragma unroll
  for (int i = 0; i < 2; ++i)
#pragma unroll
    for (int j = 0; j < 2; ++j) acc[i][j] = (f32x4){0.f, 0.f, 0.f, 0.f};

  for (int kt = 0; kt < Kd; kt += 32) {
    if (aIsBf16) {
      short8v v = *(const short8v*)((const short*)A + (size_t)(row0 + ar) * Kd + kt + ak);
      *(short8v*)&As[ar][ak] = v;
    } else {
      const float* ap = (const float*)A + (size_t)(row0 + ar) * Kd + kt + ak;
      float4 f0 = *(const float4*)ap;
      float4 f1 = *(const float4*)(ap + 4);
      short8v v;
      v[0] = (short)f2bf(f0.x); v[1] = (short)f2bf(f0.y);
      v[2] = (short)f2bf(f0.z); v[3] = (short)f2bf(f0.w);
      v[4] = (short)f2bf(f1.x); v[5] = (short)f2bf(f1.y);
      v[6] = (short)f2bf(f1.z); v[7] = (short)f2bf(f1.w);
      *(short8v*)&As[ar][ak] = v;
    }
    {
      const float* wp = W + (size_t)(kt + wk) * N + col0 + wn8;
      float4 f0 = *(const float4*)wp;
      float4 f1 = *(const float4*)(wp + 4);
      Bs[wn8 + 0][wk] = (short)f2bf(f0.x);
      Bs[wn8 + 1][wk] = (short)f2bf(f0.y);
      Bs[wn8 + 2][wk] = (short)f2bf(f0.z);
      Bs[wn8 + 3][wk] = (short)f2bf(f0.w);
      Bs[wn8 + 4][wk] = (short)f2bf(f1.x);
      Bs[wn8 + 5][wk] = (short)f2bf(f1.y);
      Bs[wn8 + 6][wk] = (short)f2bf(f1.z);
      Bs[wn8 + 7][wk] = (short)f2bf(f1.w);
    }
    __syncthreads();

    short8v a0 = *(const short8v*)&As[wm * 32 + lc16][g * 8];
    short8v a1 = *(const short8v*)&As[wm * 32 + 16 + lc16][g * 8];
    short8v b0 = *(const short8v*)&Bs[wn * 32 + lc16][g * 8];
    short8v b1 = *(const short8v*)&Bs[wn * 32 + 16 + lc16][g * 8];
    acc[0][0] = __builtin_amdgcn_mfma_f32_16x16x32_bf16(a0, b0, acc[0][0], 0, 0, 0);
    acc[0][1] = __builtin_amdgcn_mfma_f32_16x16x32_bf16(a0, b1, acc[0][1], 0, 0, 0);
    acc[1][0] = __builtin_amdgcn_mfma_f32_16x16x32_bf16(a1, b0, acc[1][0], 0, 0, 0);
    acc[1][1] = __builtin_amdgcn_mfma_f32_16x16x32_bf16(a1, b1, acc[1][1], 0, 0, 0);
    __syncthreads();
  }

#pragma unroll
  for (int ni = 0; ni < 2; ++ni) {
    const int ocol = col0 + wn * 32 + ni * 16 + lc16;
    const float bb = bias[ocol];
#pragma unroll
    for (int mi = 0; mi < 2; ++mi)
#pragma unroll
      for (int r = 0; r < 4; ++r) {
        const int orow = row0 + wm * 32 + mi * 16 + g * 4 + r;
        const float val = acc[mi][ni][r] + bb;
        if (mode == 0) {
          Cf[(size_t)orow * N + ocol] = val;
        } else {
          const int bI = orow >> 11, s = orow & 2047;
          const int hI = ocol >> 6, dh = ocol & 63;
          Cbf[(((size_t)(bI * TH + hI) * TS + s) * TDH) + dh] = (short)f2bf(val);
        }
      }
  }
}

// ---------------------------------------------------------------------------
// Fused attention v5: LDS-staged K (GEMM anatomy), 64 q-rows/block.
// 4 waves; wave owns 16 rows x all 2048 cols (rows never cross waves ->
// admission/Michelot barrier-free). K chunks (128x64 bf16 = 16 KB) staged
// global->reg->LDS, double-buffered, XOR-swizzled (16-way -> 2-way banks).
// Two-pass exact threshold tau0 = zmax-1 (proven R6). Candidate lists in
// LDS; Michelot per 16-lane group; sparse PV + avg scatter; dense fallback.
// MFMA C/D: col = lane&15, row = (lane>>4)*4 + reg.
// ---------------------------------------------------------------------------
__global__ __launch_bounds__(256, 2) void fused_attn(
    const short* __restrict__ Qh, const short* __restrict__ Kh,
    const float* __restrict__ V, short* __restrict__ heads,
    float* __restrict__ avg)
{
  __shared__ short Ks[2][CHUNK * TDH];        // 2 x 16 KB, swizzled units
  __shared__ unsigned short idxS[ROWS][CAP];  // 12 KB
  __shared__ float valS[ROWS][CAP];           // 24 KB (overlaid zrow in fallback)
  __shared__ float redMax[ROWS];
  __shared__ int   cntS[ROWS];
  __shared__ float tauS[ROWS];
  __shared__ float redA[4], redB[4], redMx[4];
  __shared__ float qrowS[TDH];

  const int tid  = threadIdx.x;
  const int w    = tid >> 6;
  const int lane = tid & 63;
  const int g    = lane >> 4;
  const int lc16 = lane & 15;
  const int pair = blockIdx.y;
  const int b    = pair >> 3;
  const int h    = pair & 7;
  const int q0   = blockIdx.x * ROWS;
  const int rw0  = w * 16;                    // wave's first local row

  const short* Qbase = Qh + ((size_t)pair * TS + q0) * TDH;
  const short* Kb    = Kh + (size_t)pair * TS * TDH;
  const float* Vb    = V + (size_t)b * TS * TDH;

  // A-fragments: wave's 16 q-rows
  short8v aq0 = *(const short8v*)(Qbase + (rw0 + lc16) * TDH + g * 8);
  short8v aq1 = *(const short8v*)(Qbase + (rw0 + lc16) * TDH + 32 + g * 8);

  if (tid < ROWS) cntS[tid] = 0;

  float runmax[4] = {-1e30f, -1e30f, -1e30f, -1e30f};
  float tau0[4] = {0.f, 0.f, 0.f, 0.f};
  const int sx = lc16 & 7;

  for (int pass = 0; pass < 2; ++pass) {
    if (pass == 1) {
      // finalize row maxima -> tau0 (wave-local rows)
#pragma unroll
      for (int m = 1; m < 16; m <<= 1)
#pragma unroll
        for (int i = 0; i < 4; ++i) runmax[i] = fmaxf(runmax[i], __shfl_xor(runmax[i], m));
      if (lc16 == 0)
#pragma unroll
        for (int i = 0; i < 4; ++i) redMax[rw0 + g * 4 + i] = runmax[i];
    }
    // stage chunk 0 into buf 0 (swizzled)
#pragma unroll
    for (int j = 0; j < 4; ++j) {
      const int v = j * 256 + tid;
      short8v d = *(const short8v*)(Kb + (size_t)v * 8);
      *(short8v*)&Ks[0][(v ^ ((v >> 3) & 7)) * 8] = d;
    }
    __syncthreads();
    if (pass == 1)
#pragma unroll
      for (int i = 0; i < 4; ++i) tau0[i] = redMax[rw0 + g * 4 + i] - 1.0f;

    for (int c = 0; c < NCH; ++c) {
      const int cur = c & 1;
      short8v nx[4];
      const bool more = (c + 1 < NCH);
      if (more) {
        const short* src = Kb + (size_t)(c + 1) * CHUNK * TDH;
#pragma unroll
        for (int j = 0; j < 4; ++j) nx[j] = *(const short8v*)(src + (size_t)(j * 256 + tid) * 8);
      }
      // compute 8 col-tiles from LDS
      f32x4 acc[8];
#pragma unroll
      for (int t = 0; t < 8; ++t) acc[t] = (f32x4){0.f, 0.f, 0.f, 0.f};
#pragma unroll
      for (int t = 0; t < 8; ++t) {
        const int rowu = (t * 16 + lc16) * 8;
        short8v b0 = *(const short8v*)&Ks[cur][(rowu + (g ^ sx)) * 8];
        short8v b1 = *(const short8v*)&Ks[cur][(rowu + ((4 + g) ^ sx)) * 8];
        acc[t] = __builtin_amdgcn_mfma_f32_16x16x32_bf16(aq0, b0, acc[t], 0, 0, 0);
        acc[t] = __builtin_amdgcn_mfma_f32_16x16x32_bf16(aq1, b1, acc[t], 0, 0, 0);
      }
      if (pass == 0) {
#pragma unroll
        for (int t = 0; t < 8; ++t)
#pragma unroll
          for (int i = 0; i < 4; ++i) runmax[i] = fmaxf(runmax[i], acc[t][i]);
      } else {
#pragma unroll
        for (int t = 0; t < 8; ++t)
#pragma unroll
          for (int i = 0; i < 4; ++i) {
            const float v = acc[t][i];
            if (v > tau0[i]) {
              const int row = rw0 + g * 4 + i;
              const int pos = atomicAdd(&cntS[row], 1);
              if (pos < CAP) {
                idxS[row][pos] = (unsigned short)(c * CHUNK + t * 16 + lc16);
                valS[row][pos] = v;
              }
            }
          }
      }
      if (more) {
#pragma unroll
        for (int j = 0; j < 4; ++j) {
          const int v = j * 256 + tid;
          *(short8v*)&Ks[cur ^ 1][(v ^ ((v >> 3) & 7)) * 8] = nx[j];
        }
      }
      __syncthreads();
    }
  }

  // ---- Michelot per 16-lane group on its 4 rows (wave-local, no barriers) --
#pragma unroll
  for (int i = 0; i < 4; ++i) {
    const int r = rw0 + g * 4 + i;
    const int cnt = cntS[r];
    float tau_r = redMax[r] - 1.0f;
    if (cnt <= CAP) {
      float cv[CAP / 16];
#pragma unroll
      for (int e = 0; e < CAP / 16; ++e) {
        const int ii = lc16 + e * 16;
        cv[e] = (ii < cnt) ? valS[r][ii] : -1e30f;
      }
      int prevc = -1;
      for (int it = 0; it < 64; ++it) {
        float s = 0.f, c = 0.f;
#pragma unroll
        for (int e = 0; e < CAP / 16; ++e) {
          if (cv[e] > tau_r) { s += cv[e]; c += 1.f; }
        }
#pragma unroll
        for (int m = 1; m < 16; m <<= 1) {
          s += __shfl_xor(s, m);
          c += __shfl_xor(c, m);
        }
        tau_r = (s - 1.f) / c;
        const int ci = (int)c;
        if (ci == prevc) break;
        prevc = ci;
      }
    }
    if (lc16 == 0) tauS[r] = tau_r;
  }

  // ---- avg scatter + batched sparse PV over wave's 16 rows ----
  for (int rr = 0; rr < 16; ++rr) {
    const int r = rw0 + rr;
    const int cnt = cntS[r];
    if (cnt > CAP) continue;                   // fallback handles
    const float tau_r = tauS[r];
    float* avgRow = avg + ((size_t)b * TS + q0 + r) * TS;
    for (int e = lane; e < cnt; e += 64) {
      const float p = valS[r][e] - tau_r;
      if (p > 0.f) atomicAdd(avgRow + idxS[r][e], p * 0.125f);
    }
    float a = 0.f;
    for (int e0 = 0; e0 < cnt; e0 += 8) {
      float pb[8], vb8[8];
#pragma unroll
      for (int u = 0; u < 8; ++u) {
        const int e = e0 + u;
        const int ec = (e < cnt) ? e : 0;
        pb[u] = (e < cnt) ? (valS[r][ec] - tau_r) : 0.f;
        vb8[u] = Vb[(size_t)idxS[r][ec] * TDH + lane];
      }
#pragma unroll
      for (int u = 0; u < 8; ++u) a += fmaxf(pb[u], 0.f) * vb8[u];
    }
    heads[((size_t)b * TS + q0 + r) * TD + h * TDH + lane] = (short)f2bf(a);
  }

  // ---- dense fallback for overflowed rows (recompute; rare) ----
  const int anyOver = __syncthreads_or((tid < ROWS) ? (cntS[tid] > CAP) : 0);
  if (anyOver) {
    float* zrow = &valS[0][0];                 // 64*96 floats >= 2048
    float* hp   = (float*)&idxS[0][0];         // 4*64 floats
    for (int r = 0; r < ROWS; ++r) {
      if (cntS[r] <= CAP) continue;            // uniform
      if (tid < TDH) qrowS[tid] = bf2f((unsigned short)Qbase[r * TDH + tid]);
      __syncthreads();
      for (int u = 0; u < 8; ++u) {
        const int j = tid * 8 + u;
        const short* kr = Kb + (size_t)j * TDH;
        float s = 0.f;
        for (int d = 0; d < TDH; ++d) s += qrowS[d] * bf2f((unsigned short)kr[d]);
        zrow[j] = s;
      }
      __syncthreads();
      float lmax = -1e30f;
#pragma unroll
      for (int jj = 0; jj < 8; ++jj) lmax = fmaxf(lmax, zrow[(jj << 8) + tid]);
      for (int off = 32; off; off >>= 1) lmax = fmaxf(lmax, __shfl_down(lmax, off));
      if (lane == 0) redMx[w] = lmax;
      __syncthreads();
      float tau = fmaxf(fmaxf(redMx[0], redMx[1]), fmaxf(redMx[2], redMx[3])) - 1.0f;
      int prevc = -1;
      for (int it = 0; it < 64; ++it) {
        float ls = 0.f, lc = 0.f;
#pragma unroll
        for (int jj = 0; jj < 8; ++jj) {
          const float v = zrow[(jj << 8) + tid];
          if (v > tau) { ls += v; lc += 1.f; }
        }
        for (int off = 32; off; off >>= 1) {
          ls += __shfl_down(ls, off);
          lc += __shfl_down(lc, off);
        }
        if (lane == 0) { redA[w] = ls; redB[w] = lc; }
        __syncthreads();
        const float ts = redA[0] + redA[1] + redA[2] + redA[3];
        const float tc = redB[0] + redB[1] + redB[2] + redB[3];
        tau = (ts - 1.f) / tc;
        const int ci = (int)tc;
        __syncthreads();
        if (ci == prevc) break;
        prevc = ci;
      }
      float* avgRow = avg + ((size_t)b * TS + q0 + r) * TS;
#pragma unroll
      for (int jj = 0; jj < 8; ++jj) {
        const int j = (jj << 8) + tid;
        const float p = zrow[j] - tau;
        if (p > 0.f) atomicAdd(avgRow + j, p * 0.125f);
      }
      float a = 0.f;
      for (int j = 0; j < 512; ++j) {
        const float p = zrow[w * 512 + j] - tau;
        if (p > 0.f) a += p * Vb[(size_t)(w * 512 + j) * TDH + lane];
      }
      hp[w * 64 + lane] = a;
      __syncthreads();
      if (w == 0)
        heads[((size_t)b * TS + q0 + r) * TD + h * TDH + lane] =
            (short)f2bf((hp[lane] + hp[64 + lane]) + (hp[128 + lane] + hp[192 + lane]));
      __syncthreads();
    }
  }
}

// ---------------------------------------------------------------------------
extern "C" void kernel_launch(void* const* d_in, const int* in_sizes, int n_in,
                              void* d_out, int out_size, void* d_ws, size_t ws_size,
                              hipStream_t stream) {
  (void)in_sizes; (void)n_in; (void)out_size; (void)ws_size;

  const float* x    = (const float*)d_in[0];
  const float* Wq   = (const float*)d_in[1];
  const float* bq   = (const float*)d_in[2];
  const float* Wk   = (const float*)d_in[3];
  const float* bk   = (const float*)d_in[4];
  const float* Wv   = (const float*)d_in[5];
  const float* bv   = (const float*)d_in[6];
  const float* Wout = (const float*)d_in[7];
  const float* bout = (const float*)d_in[8];

  float* out   = (float*)d_out;
  float* x_out = out;                       // [2,2048,512]
  float* avg   = out + 2097152;             // [2,2048,2048]

  float* ws = (float*)d_ws;
  float* Vb = ws;                           // f32 [2][2048][64]
  short* Hd = (short*)(ws + 262144);        // bf16 [4096][512]
  short* Qh = (short*)(ws + 1310720);       // bf16 [16][2048][64]
  short* Kh = (short*)(ws + 2359296);       // bf16 [16][2048][64]

  const dim3 blk(256);
  const int BS = 2 * TS;

  gemm_mfma<<<dim3(BS / 64, TD / 64), blk, 0, stream>>>(x, 0, Wq, bq, nullptr, Qh, 1, BS, TD, TD);
  gemm_mfma<<<dim3(BS / 64, TD / 64), blk, 0, stream>>>(x, 0, Wk, bk, nullptr, Kh, 1, BS, TD, TD);
  gemm_mfma<<<dim3(BS / 64, TDH / 64), blk, 0, stream>>>(x, 0, Wv, bv, Vb, nullptr, 0, BS, TDH, TD);

  hipMemsetAsync(avg, 0, (size_t)2 * TS * TS * sizeof(float), stream);

  fused_attn<<<dim3(TS / ROWS, 16), blk, 0, stream>>>(Qh, Kh, Vb, Hd, avg);

  gemm_mfma<<<dim3(BS / 64, TD / 64), blk, 0, stream>>>(Hd, 1, Wout, bout, x_out, nullptr, 0, BS, TD, TD);
}

// Round 8
// 255.308 us; speedup vs baseline: 1.9370x; 1.1662x over previous
//
#include <hip/hip_runtime.h>
#include <cstddef>
#include <cstdint>

#define TS 2048   // sequence length S
#define TD 512    // model dim D
#define TH 8      // heads
#define TDH 64    // head dim
#define CAP 192   // candidate entries per head-row; dense fallback beyond

typedef float f32x4 __attribute__((ext_vector_type(4)));
typedef short short8v __attribute__((ext_vector_type(8)));

__device__ __forceinline__ unsigned short f2bf(float f) {
  unsigned u = __builtin_bit_cast(unsigned, f);
  u += 0x7fff + ((u >> 16) & 1);          // RNE
  return (unsigned short)(u >> 16);
}

// ---------------------------------------------------------------------------
// bf16-MFMA GEMM (proven R6/R7): C = A @ W + bias.
// ---------------------------------------------------------------------------
__global__ __launch_bounds__(256) void gemm_mfma(
    const void* __restrict__ A, int aIsBf16,
    const float* __restrict__ W, const float* __restrict__ bias,
    float* __restrict__ Cf, short* __restrict__ Cbf, int mode,
    int M, int N, int Kd)
{
  __shared__ short As[64][40];
  __shared__ short Bs[64][40];

  const int tid  = threadIdx.x;
  const int w    = tid >> 6;
  const int lane = tid & 63;
  const int g    = lane >> 4;
  const int lc16 = lane & 15;
  const int wm   = w >> 1;
  const int wn   = w & 1;
  const int row0 = blockIdx.x * 64;
  const int col0 = blockIdx.y * 64;

  const int ar = tid >> 2;
  const int ak = (tid & 3) << 3;
  const int wk = tid >> 3;
  const int wn8 = (tid & 7) << 3;

  f32x4 acc[2][2];
#pragma unroll
  for (int i = 0; i < 2; ++i)
#pragma unroll
    for (int j = 0; j < 2; ++j) acc[i][j] = (f32x4){0.f, 0.f, 0.f, 0.f};

  for (int kt = 0; kt < Kd; kt += 32) {
    if (aIsBf16) {
      short8v v = *(const short8v*)((const short*)A + (size_t)(row0 + ar) * Kd + kt + ak);
      *(short8v*)&As[ar][ak] = v;
    } else {
      const float* ap = (const float*)A + (size_t)(row0 + ar) * Kd + kt + ak;
      float4 f0 = *(const float4*)ap;
      float4 f1 = *(const float4*)(ap + 4);
      short8v v;
      v[0] = (short)f2bf(f0.x); v[1] = (short)f2bf(f0.y);
      v[2] = (short)f2bf(f0.z); v[3] = (short)f2bf(f0.w);
      v[4] = (short)f2bf(f1.x); v[5] = (short)f2bf(f1.y);
      v[6] = (short)f2bf(f1.z); v[7] = (short)f2bf(f1.w);
      *(short8v*)&As[ar][ak] = v;
    }
    {
      const float* wp = W + (size_t)(kt + wk) * N + col0 + wn8;
      float4 f0 = *(const float4*)wp;
      float4 f1 = *(const float4*)(wp + 4);
      Bs[wn8 + 0][wk] = (short)f2bf(f0.x);
      Bs[wn8 + 1][wk] = (short)f2bf(f0.y);
      Bs[wn8 + 2][wk] = (short)f2bf(f0.z);
      Bs[wn8 + 3][wk] = (short)f2bf(f0.w);
      Bs[wn8 + 4][wk] = (short)f2bf(f1.x);
      Bs[wn8 + 5][wk] = (short)f2bf(f1.y);
      Bs[wn8 + 6][wk] = (short)f2bf(f1.z);
      Bs[wn8 + 7][wk] = (short)f2bf(f1.w);
    }
    __syncthreads();

    short8v a0 = *(const short8v*)&As[wm * 32 + lc16][g * 8];
    short8v a1 = *(const short8v*)&As[wm * 32 + 16 + lc16][g * 8];
    short8v b0 = *(const short8v*)&Bs[wn * 32 + lc16][g * 8];
    short8v b1 = *(const short8v*)&Bs[wn * 32 + 16 + lc16][g * 8];
    acc[0][0] = __builtin_amdgcn_mfma_f32_16x16x32_bf16(a0, b0, acc[0][0], 0, 0, 0);
    acc[0][1] = __builtin_amdgcn_mfma_f32_16x16x32_bf16(a0, b1, acc[0][1], 0, 0, 0);
    acc[1][0] = __builtin_amdgcn_mfma_f32_16x16x32_bf16(a1, b0, acc[1][0], 0, 0, 0);
    acc[1][1] = __builtin_amdgcn_mfma_f32_16x16x32_bf16(a1, b1, acc[1][1], 0, 0, 0);
    __syncthreads();
  }

#pragma unroll
  for (int ni = 0; ni < 2; ++ni) {
    const int ocol = col0 + wn * 32 + ni * 16 + lc16;
    const float bb = bias[ocol];
#pragma unroll
    for (int mi = 0; mi < 2; ++mi)
#pragma unroll
      for (int r = 0; r < 4; ++r) {
        const int orow = row0 + wm * 32 + mi * 16 + g * 4 + r;
        const float val = acc[mi][ni][r] + bb;
        if (mode == 0) {
          Cf[(size_t)orow * N + ocol] = val;
        } else {
          const int bI = orow >> 11, s = orow & 2047;
          const int hI = ocol >> 6, dh = ocol & 63;
          Cbf[(((size_t)(bI * TH + hI) * TS + s) * TDH) + dh] = (short)f2bf(val);
        }
      }
  }
}

// ---------------------------------------------------------------------------
// zgemm: Z[q][j] = sum_d Q[pair][q][d] * K[pair][j][d]  (f32 out, slab rows)
// Pure register NT-GEMM: no LDS, no barriers. Block = 64 q x 256 j, one head.
// Operands swapped (mfma(K,Q)) so D-col(lane&15) = q, D-row(g*4+i) = j:
// each lane's 4 acc values are 4 consecutive j -> one float4 store per tile.
// ---------------------------------------------------------------------------
__global__ __launch_bounds__(256) void zgemm(
    const short* __restrict__ Qh, const short* __restrict__ Kh,
    float* __restrict__ Zs, int bsel, int q0s, int qc)
{
  const int tid  = threadIdx.x;
  const int w    = tid >> 6;
  const int lane = tid & 63;
  const int g    = lane >> 4;
  const int lc16 = lane & 15;
  const int h    = blockIdx.z;
  const int pair = bsel * TH + h;
  const int jb   = blockIdx.x * 256 + w * 64;
  const int qlb  = blockIdx.y * 64;           // slab-local q base
  const int qb   = q0s + qlb;                 // global q base

  const short* Qp = Qh + (size_t)pair * TS * TDH;
  const short* Kp = Kh + (size_t)pair * TS * TDH;

  // B-frags: Q rows (4 q-subtiles), resident
  short8v bq[4][2];
#pragma unroll
  for (int ct = 0; ct < 4; ++ct) {
    const short* qp = Qp + (size_t)(qb + ct * 16 + lc16) * TDH + g * 8;
    bq[ct][0] = *(const short8v*)qp;
    bq[ct][1] = *(const short8v*)(qp + 32);
  }

  f32x4 acc[4][4];
#pragma unroll
  for (int rt = 0; rt < 4; ++rt)
#pragma unroll
    for (int ct = 0; ct < 4; ++ct) acc[rt][ct] = (f32x4){0.f, 0.f, 0.f, 0.f};

#pragma unroll
  for (int rt = 0; rt < 4; ++rt) {
    const short* kp = Kp + (size_t)(jb + rt * 16 + lc16) * TDH + g * 8;
    short8v ak0 = *(const short8v*)kp;
    short8v ak1 = *(const short8v*)(kp + 32);
#pragma unroll
    for (int ct = 0; ct < 4; ++ct) {
      acc[rt][ct] = __builtin_amdgcn_mfma_f32_16x16x32_bf16(ak0, bq[ct][0], acc[rt][ct], 0, 0, 0);
      acc[rt][ct] = __builtin_amdgcn_mfma_f32_16x16x32_bf16(ak1, bq[ct][1], acc[rt][ct], 0, 0, 0);
    }
  }

  // store: q = qlb + ct*16 + lc16 (slab-local), j = jb + rt*16 + g*4 + i
#pragma unroll
  for (int rt = 0; rt < 4; ++rt)
#pragma unroll
    for (int ct = 0; ct < 4; ++ct) {
      float4 o = {acc[rt][ct][0], acc[rt][ct][1], acc[rt][ct][2], acc[rt][ct][3]};
      *(float4*)&Zs[((size_t)h * qc + qlb + ct * 16 + lc16) * TS + jb + rt * 16 + g * 4] = o;
    }
}

// ---------------------------------------------------------------------------
// sparsemax_pv: one block per (b, q) row; ALL 8 heads together.
// Load 8 head-rows of Z (f32, coalesced). Per head: zmax -> tau0 = zmax-1
// (exact), candidate lists in LDS, wave-local list-Michelot (heads 2w,2w+1).
// avg row computed densely in regs, written once (no atomics, no memset).
// Sparse PV per head. Dense LDS fallback for overflowed heads (rare).
// ---------------------------------------------------------------------------
__global__ __launch_bounds__(256) void sparsemax_pv(
    const float* __restrict__ Zs, const float* __restrict__ V,
    short* __restrict__ heads, float* __restrict__ avg,
    int bsel, int q0s, int qc)
{
  __shared__ unsigned short idxH[TH][CAP];   // 3 KB
  __shared__ float valH[TH][CAP];            // 6 KB
  __shared__ int   cntH[TH];
  __shared__ float redM[4][TH];
  __shared__ float tauS[TH];
  __shared__ float zdense[TS];               // 8 KB (fallback only)
  __shared__ float redA[4], redB[4];
  __shared__ float hp[4][TDH];               // 1 KB

  const int tid  = threadIdx.x;
  const int w    = tid >> 6;
  const int lane = tid & 63;
  const int ql   = blockIdx.x;
  const int q    = q0s + ql;
  const int row  = bsel * TS + q;

  if (tid < TH) cntH[tid] = 0;

  // ---- load 8 head-rows (this thread's 8 cols each), all independent ----
  float za[TH][8];
#pragma unroll
  for (int h = 0; h < TH; ++h) {
    const float* zp = Zs + ((size_t)h * qc + ql) * TS + (tid << 3);
    float4 a0 = *(const float4*)zp;
    float4 a1 = *(const float4*)(zp + 4);
    za[h][0] = a0.x; za[h][1] = a0.y; za[h][2] = a0.z; za[h][3] = a0.w;
    za[h][4] = a1.x; za[h][5] = a1.y; za[h][6] = a1.z; za[h][7] = a1.w;
  }

  // ---- per-head row max (64-lane shfl reduce, cross-wave via LDS) ----
  float mx[TH];
#pragma unroll
  for (int h = 0; h < TH; ++h) {
    float m = za[h][0];
#pragma unroll
    for (int j = 1; j < 8; ++j) m = fmaxf(m, za[h][j]);
    mx[h] = m;
  }
#pragma unroll
  for (int m = 1; m < 64; m <<= 1)
#pragma unroll
    for (int h = 0; h < TH; ++h) mx[h] = fmaxf(mx[h], __shfl_xor(mx[h], m));
  if (lane == 0)
#pragma unroll
    for (int h = 0; h < TH; ++h) redM[w][h] = mx[h];
  __syncthreads();

  float tau0[TH];
#pragma unroll
  for (int h = 0; h < TH; ++h)
    tau0[h] = fmaxf(fmaxf(redM[0][h], redM[1][h]),
                    fmaxf(redM[2][h], redM[3][h])) - 1.0f;

  // ---- admission: z > zmax-1 (exact superset of support) ----
#pragma unroll
  for (int h = 0; h < TH; ++h)
#pragma unroll
    for (int j = 0; j < 8; ++j) {
      const float v = za[h][j];
      if (v > tau0[h]) {
        const int pos = atomicAdd(&cntH[h], 1);
        if (pos < CAP) {
          idxH[h][pos] = (unsigned short)((tid << 3) + j);
          valH[h][pos] = v;
        }
      }
    }
  __syncthreads();

  // ---- list-Michelot: wave w owns heads 2w, 2w+1 (barrier-free) ----
  for (int hh = 0; hh < 2; ++hh) {
    const int h = w * 2 + hh;
    const int cnt = cntH[h];
    if (cnt <= CAP) {
      float cv[CAP / 64 + 1];
#pragma unroll
      for (int e = 0; e < CAP / 64; ++e) {
        const int ii = lane + e * 64;
        cv[e] = (ii < cnt) ? valH[h][ii] : -1e30f;
      }
      float tau = tau0[h];
      int prevc = -1;
      for (int it = 0; it < 64; ++it) {
        float s = 0.f, c = 0.f;
#pragma unroll
        for (int e = 0; e < CAP / 64; ++e) {
          if (cv[e] > tau) { s += cv[e]; c += 1.f; }
        }
#pragma unroll
        for (int m = 1; m < 64; m <<= 1) {
          s += __shfl_xor(s, m);
          c += __shfl_xor(c, m);
        }
        tau = (s - 1.f) / c;
        const int ci = (int)c;
        if (ci == prevc) break;
        prevc = ci;
      }
      if (lane == 0) tauS[h] = tau;
    }
  }

  // ---- dense fallback for overflowed heads (rare) ----
  const int over = (tid < TH) ? (cntH[tid] > CAP) : 0;
  const float* Vb = V + (size_t)bsel * TS * TDH;
  if (__syncthreads_or(over)) {
#pragma unroll
    for (int h = 0; h < TH; ++h) {
      if (cntH[h] <= CAP) continue;           // uniform branch
#pragma unroll
      for (int j = 0; j < 8; ++j) zdense[(tid << 3) + j] = za[h][j];
      __syncthreads();
      float tau = tau0[h];
      int prevc = -1;
      for (int it = 0; it < 64; ++it) {
        float ls = 0.f, lc = 0.f;
#pragma unroll
        for (int jj = 0; jj < 8; ++jj) {
          const float v = zdense[(jj << 8) + tid];
          if (v > tau) { ls += v; lc += 1.f; }
        }
        for (int off = 32; off; off >>= 1) {
          ls += __shfl_down(ls, off);
          lc += __shfl_down(lc, off);
        }
        if (lane == 0) { redA[w] = ls; redB[w] = lc; }
        __syncthreads();
        const float ts = redA[0] + redA[1] + redA[2] + redA[3];
        const float tc = redB[0] + redB[1] + redB[2] + redB[3];
        tau = (ts - 1.f) / tc;
        const int ci = (int)tc;
        __syncthreads();
        if (ci == prevc) break;
        prevc = ci;
      }
      if (tid == 0) tauS[h] = tau;
      // dense PV: wave covers 512 cols, lane = dh
      float a = 0.f;
      for (int j = w * 512; j < w * 512 + 512; ++j) {
        const float p = zdense[j] - tau;
        if (p > 0.f) a += p * Vb[(size_t)j * TDH + lane];
      }
      hp[w][lane] = a;
      __syncthreads();
      if (w == 0)
        heads[(size_t)row * TD + h * TDH + lane] =
            (short)f2bf((hp[0][lane] + hp[1][lane]) + (hp[2][lane] + hp[3][lane]));
      __syncthreads();
    }
  }

  // ---- avg row: dense compute in regs, one coalesced write, no atomics ----
  float av[8] = {0.f, 0.f, 0.f, 0.f, 0.f, 0.f, 0.f, 0.f};
#pragma unroll
  for (int h = 0; h < TH; ++h) {
    const float th = tauS[h];
#pragma unroll
    for (int j = 0; j < 8; ++j) av[j] += fmaxf(za[h][j] - th, 0.f);
  }
  {
    float4 o0 = {av[0] * 0.125f, av[1] * 0.125f, av[2] * 0.125f, av[3] * 0.125f};
    float4 o1 = {av[4] * 0.125f, av[5] * 0.125f, av[6] * 0.125f, av[7] * 0.125f};
    float* ap = avg + (size_t)row * TS + (tid << 3);
    *(float4*)ap = o0;
    *(float4*)(ap + 4) = o1;
  }

  // ---- sparse PV for normal heads: wave w owns heads 2w, 2w+1 ----
  for (int hh = 0; hh < 2; ++hh) {
    const int h = w * 2 + hh;
    const int cnt = cntH[h];
    if (cnt > CAP) continue;                   // fallback already wrote
    const float tau = tauS[h];
    float a = 0.f;
    for (int e0 = 0; e0 < cnt; e0 += 8) {
      float pb[8], vb8[8];
#pragma unroll
      for (int u = 0; u < 8; ++u) {
        const int e = e0 + u;
        const int ec = (e < cnt) ? e : 0;
        pb[u] = (e < cnt) ? (valH[h][ec] - tau) : 0.f;
        vb8[u] = Vb[(size_t)idxH[h][ec] * TDH + lane];
      }
#pragma unroll
      for (int u = 0; u < 8; ++u) a += fmaxf(pb[u], 0.f) * vb8[u];
    }
    heads[(size_t)row * TD + h * TDH + lane] = (short)f2bf(a);
  }
}

// ---------------------------------------------------------------------------
extern "C" void kernel_launch(void* const* d_in, const int* in_sizes, int n_in,
                              void* d_out, int out_size, void* d_ws, size_t ws_size,
                              hipStream_t stream) {
  (void)in_sizes; (void)n_in; (void)out_size;

  const float* x    = (const float*)d_in[0];
  const float* Wq   = (const float*)d_in[1];
  const float* bq   = (const float*)d_in[2];
  const float* Wk   = (const float*)d_in[3];
  const float* bk   = (const float*)d_in[4];
  const float* Wv   = (const float*)d_in[5];
  const float* bv   = (const float*)d_in[6];
  const float* Wout = (const float*)d_in[7];
  const float* bout = (const float*)d_in[8];

  float* out   = (float*)d_out;
  float* x_out = out;                       // [2,2048,512]
  float* avg   = out + 2097152;             // [2,2048,2048]

  float* ws = (float*)d_ws;
  float* Vb = ws;                           // f32 [2][2048][64]   (262144 fl)
  short* Hd = (short*)(ws + 262144);        // bf16 [4096][512]    (1048576 fl)
  short* Qh = (short*)(ws + 1310720);       // bf16 [16][2048][64] (1048576 fl)
  short* Kh = (short*)(ws + 2359296);       // bf16 [16][2048][64] (1048576 fl)
  float* Zs = ws + 3407872;                 // f32 slab [8][qc][2048]

  // pick largest q-chunk that fits the workspace
  const size_t wsFloats = ws_size / 4;
  const size_t base = 3407872;
  int qc = 64;
  for (int cand = 2048; cand >= 64; cand >>= 1) {
    if (base + (size_t)TH * cand * TS <= wsFloats) { qc = cand; break; }
  }

  const dim3 blk(256);
  const int BS = 2 * TS;                    // 4096 rows

  // projections (bf16 MFMA; Q,K -> bf16 head-major, V -> f32)
  gemm_mfma<<<dim3(BS / 64, TD / 64), blk, 0, stream>>>(x, 0, Wq, bq, nullptr, Qh, 1, BS, TD, TD);
  gemm_mfma<<<dim3(BS / 64, TD / 64), blk, 0, stream>>>(x, 0, Wk, bk, nullptr, Kh, 1, BS, TD, TD);
  gemm_mfma<<<dim3(BS / 64, TDH / 64), blk, 0, stream>>>(x, 0, Wv, bv, Vb, nullptr, 0, BS, TDH, TD);

  // attention, slabbed over (batch, q-chunk)
  for (int bsel = 0; bsel < 2; ++bsel)
    for (int q0s = 0; q0s < TS; q0s += qc) {
      zgemm<<<dim3(TS / 256, qc / 64, TH), blk, 0, stream>>>(Qh, Kh, Zs, bsel, q0s, qc);
      sparsemax_pv<<<dim3(qc), blk, 0, stream>>>(Zs, Vb, Hd, avg, bsel, q0s, qc);
    }

  // output projection (A = bf16 heads)
  gemm_mfma<<<dim3(BS / 64, TD / 64), blk, 0, stream>>>(Hd, 1, Wout, bout, x_out, nullptr, 0, BS, TD, TD);
}